// Round 3
// baseline (84.755 us; speedup 1.0000x reference)
//
#include <hip/hip_runtime.h>
#include <hip/hip_bf16.h>

#define NE 800000   // edges
#define NN 50000    // nodes
#define TPW 2       // edge-tiles (of 16 edges) per wave

typedef __attribute__((ext_vector_type(8))) short        s16x8;
typedef __attribute__((ext_vector_type(8))) __bf16       bf16x8;
typedef __attribute__((ext_vector_type(4))) float        f32x4;
typedef __attribute__((ext_vector_type(2))) float        f32x2;
typedef __attribute__((ext_vector_type(4))) unsigned int u32x4;
typedef __attribute__((ext_vector_type(2))) unsigned int u32x2;

// ws layout (unsigned short elems):
//   [0)        w1t [64][160]   10240   (k<130: W1^T; k==130: b1; else 0)
//   [10240)    w2t [32][64]     2048
//   [12288)    w3t [16][32]      512
//   [16384)    nfb [NN][64]  bf16 node table
#define NFB_OFF 16384
#define WS_NEED ((size_t)(NFB_OFF + (size_t)NN * 64) * 2)

__device__ __forceinline__ unsigned short f2bf_bits(float f) {
    __bf16 b = (__bf16)f;
    return __builtin_bit_cast(unsigned short, b);
}

__device__ __forceinline__ unsigned int pkbf(float a, float b) {
    return (unsigned int)f2bf_bits(a) | ((unsigned int)f2bf_bits(b) << 16);
}

__device__ __forceinline__ s16x8 cvt8(f32x4 a, f32x4 b) {
    bf16x8 r;
    r[0] = (__bf16)a[0]; r[1] = (__bf16)a[1]; r[2] = (__bf16)a[2]; r[3] = (__bf16)a[3];
    r[4] = (__bf16)b[0]; r[5] = (__bf16)b[1]; r[6] = (__bf16)b[2]; r[7] = (__bf16)b[3];
    return __builtin_bit_cast(s16x8, r);
}

__global__ void prep(const float* __restrict__ W1, const float* __restrict__ b1,
                     const float* __restrict__ W2, const float* __restrict__ W3,
                     const float* __restrict__ nf, unsigned short* __restrict__ ws,
                     int do_nf) {
    unsigned short* w1t = ws;
    unsigned short* w2t = ws + 10240;
    unsigned short* w3t = ws + 12288;
    int t = blockIdx.x * blockDim.x + threadIdx.x;
    int stride = gridDim.x * blockDim.x;
    for (int i = t; i < 64 * 160; i += stride) {
        int j = i / 160, k = i % 160;
        float v = (k < 130) ? W1[k * 64 + j] : (k == 130 ? b1[j] : 0.0f);
        w1t[i] = f2bf_bits(v);
    }
    for (int i = t; i < 32 * 64; i += stride) {
        int j = i / 64, k = i % 64;
        w2t[i] = f2bf_bits(W2[k * 32 + j]);
    }
    for (int i = t; i < 16 * 32; i += stride) {
        int j = i / 32, k = i % 32;
        w3t[i] = f2bf_bits(W3[k * 16 + j]);
    }
    if (do_nf) {
        unsigned short* nfb = ws + NFB_OFF;
        for (int i = t; i < NN * 8; i += stride) {
            f32x4 a = *reinterpret_cast<const f32x4*>(nf + (long)i * 8);
            f32x4 b = *reinterpret_cast<const f32x4*>(nf + (long)i * 8 + 4);
            *reinterpret_cast<s16x8*>(nfb + (long)i * 8) = cvt8(a, b);
        }
    }
}

// Swapped-operand scheme. MFMA 16x16x32 bf16 layouts (m89-verified):
//   A: lane holds A[row=lane&15][k=(lane>>4)*8+b]   -> weights (j-major = w*t rows)
//   B: lane holds B[k=(lane>>4)*8+b][col=lane&15]   -> activations^T (col = edge)
//   D: lane holds D[row=(lane>>4)*4+r][col=lane&15] -> h[edge=lane&15][feat=...]
template <bool BF16NF>
__device__ __forceinline__ void gather4(const unsigned short* nfb, const float* nf,
                                        int si, int di, int lg, s16x8 g[4]) {
    if (BF16NF) {
        #pragma unroll
        for (int s = 0; s < 4; ++s) {
            const int row = (s < 2) ? si : di;
            g[s] = *reinterpret_cast<const s16x8*>(nfb + (long)row * 64 + (s & 1) * 32 + lg * 8);
        }
    } else {
        #pragma unroll
        for (int s = 0; s < 4; ++s) {
            const float* p = nf + (long)((s < 2) ? si : di) * 64 + (s & 1) * 32 + lg * 8;
            f32x4 a = *reinterpret_cast<const f32x4*>(p);
            f32x4 b = *reinterpret_cast<const f32x4*>(p + 4);
            g[s] = cvt8(a, b);
        }
    }
}

template <bool BF16NF>
__global__ __launch_bounds__(256) void edge_mlp(
    const float* __restrict__ nf, const int* __restrict__ ei,
    const float* __restrict__ sp, const float* __restrict__ b2,
    const float* __restrict__ b3, const unsigned short* __restrict__ wsw,
    float* __restrict__ out) {

    const unsigned short* w1t = wsw;
    const unsigned short* w2t = wsw + 10240;
    const unsigned short* w3t = wsw + 12288;
    const unsigned short* nfb = wsw + NFB_OFF;

    // per-wave bf16 redistribute buffers; row strides 72/40 shorts:
    // multiples of 8 shorts (16B) for b128 alignment, non-pow2 to cap conflicts ~4-way
    __shared__ unsigned short h1s[4 * 16 * 72];   // 9216 B
    __shared__ unsigned short h2s[4 * 16 * 40];   // 5120 B

    const int tid  = threadIdx.x;
    const int wid  = tid >> 6;
    const int lane = tid & 63;
    const int lr   = lane & 15;
    const int lg   = lane >> 4;

    // Weight A-fragments (compiler may rematerialize; loads are L1-hot).
    s16x8 w1f[5][4];
    s16x8 w2f[2][2];
    s16x8 w3f;
    #pragma unroll
    for (int s = 0; s < 5; ++s)
        #pragma unroll
        for (int c = 0; c < 4; ++c)
            w1f[s][c] = *reinterpret_cast<const s16x8*>(w1t + (c * 16 + lr) * 160 + s * 32 + lg * 8);
    #pragma unroll
    for (int s = 0; s < 2; ++s)
        #pragma unroll
        for (int c = 0; c < 2; ++c)
            w2f[s][c] = *reinterpret_cast<const s16x8*>(w2t + (c * 16 + lr) * 64 + s * 32 + lg * 8);
    w3f = *reinterpret_cast<const s16x8*>(w3t + lr * 32 + lg * 8);

    // biases per output-feature (feat = c*16 + lg*4 + r)
    f32x4 b2v[2];
    #pragma unroll
    for (int c = 0; c < 2; ++c) b2v[c] = *reinterpret_cast<const f32x4*>(b2 + c * 16 + lg * 4);
    const f32x4 b3v = *reinterpret_cast<const f32x4*>(b3 + lg * 4);

    const int tile0 = (blockIdx.x * 4 + wid) * TPW;

    int si[TPW], di[TPW];
    f32x2 spv[TPW];
    #pragma unroll
    for (int t = 0; t < TPW; ++t) {
        const int e = (tile0 + t) * 16 + lr;
        si[t] = ei[e];
        di[t] = ei[NE + e];
        spv[t] = *reinterpret_cast<const f32x2*>(sp + 2 * e);
    }

    unsigned short* h1w = h1s + wid * (16 * 72) + lr * 72;
    unsigned short* h2w = h2s + wid * (16 * 40) + lr * 40;

    s16x8 cur[4], nxt[4];
    gather4<BF16NF>(nfb, nf, si[0], di[0], lg, cur);

    #pragma unroll
    for (int tt = 0; tt < TPW; ++tt) {
        if (tt + 1 < TPW)
            gather4<BF16NF>(nfb, nf, si[tt + 1], di[tt + 1], lg, nxt);

        const int ebase = (tile0 + tt) * 16;

        // ---- layer 1 (swapped): D1 = W1^T-tiles @ x^T,  h1[edge=lr][feat] ----
        f32x4 acc1[4];
        #pragma unroll
        for (int c = 0; c < 4; ++c) acc1[c] = (f32x4){0.f, 0.f, 0.f, 0.f};

        #pragma unroll
        for (int s = 0; s < 4; ++s)
            #pragma unroll
            for (int c = 0; c < 4; ++c)
                acc1[c] = __builtin_amdgcn_mfma_f32_16x16x32_bf16(w1f[s][c], cur[s], acc1[c], 0, 0, 0);

        {   // spatial + bias K-step: k=128 (sp0), 129 (sp1), 130 (1.0 -> b1)
            unsigned int sw0 = 0u, sw1 = 0u;
            if (lg == 0) {
                sw0 = pkbf(spv[tt][0], spv[tt][1]);
                sw1 = 0x00003F80u;   // bf16(1.0) in low half (k=130), 0 in high
            }
            u32x4 sbu = {sw0, sw1, 0u, 0u};
            s16x8 sb = __builtin_bit_cast(s16x8, sbu);
            #pragma unroll
            for (int c = 0; c < 4; ++c)
                acc1[c] = __builtin_amdgcn_mfma_f32_16x16x32_bf16(w1f[4][c], sb, acc1[c], 0, 0, 0);
        }

        // relu + pack bf16, redistribute via LDS (write row = this lane's edge lr)
        #pragma unroll
        for (int c = 0; c < 4; ++c) {
            u32x2 p;
            p[0] = pkbf(fmaxf(acc1[c][0], 0.f), fmaxf(acc1[c][1], 0.f));
            p[1] = pkbf(fmaxf(acc1[c][2], 0.f), fmaxf(acc1[c][3], 0.f));
            *reinterpret_cast<u32x2*>(h1w + c * 16 + lg * 4) = p;
        }

        // ---- layer 2 (swapped): b-frag = h1[edge=lr][k=s*32+lg*8 ..+7] ----
        f32x4 acc2[2];
        #pragma unroll
        for (int c = 0; c < 2; ++c) acc2[c] = (f32x4){0.f, 0.f, 0.f, 0.f};
        #pragma unroll
        for (int s = 0; s < 2; ++s) {
            s16x8 bfr = *reinterpret_cast<const s16x8*>(h1w + s * 32 + lg * 8);
            #pragma unroll
            for (int c = 0; c < 2; ++c)
                acc2[c] = __builtin_amdgcn_mfma_f32_16x16x32_bf16(w2f[s][c], bfr, acc2[c], 0, 0, 0);
        }

        #pragma unroll
        for (int c = 0; c < 2; ++c) {
            u32x2 p;
            p[0] = pkbf(fmaxf(acc2[c][0] + b2v[c][0], 0.f), fmaxf(acc2[c][1] + b2v[c][1], 0.f));
            p[1] = pkbf(fmaxf(acc2[c][2] + b2v[c][2], 0.f), fmaxf(acc2[c][3] + b2v[c][3], 0.f));
            *reinterpret_cast<u32x2*>(h2w + c * 16 + lg * 4) = p;
        }

        // ---- layer 3 (swapped) + coalesced f32x4 store ----
        s16x8 bf3 = *reinterpret_cast<const s16x8*>(h2w + lg * 8);
        f32x4 acc3 = (f32x4){0.f, 0.f, 0.f, 0.f};
        acc3 = __builtin_amdgcn_mfma_f32_16x16x32_bf16(w3f, bf3, acc3, 0, 0, 0);

        f32x4 o;
        #pragma unroll
        for (int r = 0; r < 4; ++r) o[r] = acc3[r] + b3v[r];
        *reinterpret_cast<f32x4*>(out + (long)(ebase + lr) * 16 + lg * 4) = o;

        #pragma unroll
        for (int s = 0; s < 4; ++s) cur[s] = nxt[s];
    }
}

extern "C" void kernel_launch(void* const* d_in, const int* in_sizes, int n_in,
                              void* d_out, int out_size, void* d_ws, size_t ws_size,
                              hipStream_t stream) {
    const float* nf = (const float*)d_in[0];
    const int*   ei = (const int*)d_in[1];
    const float* sp = (const float*)d_in[2];
    const float* W1 = (const float*)d_in[3];
    const float* b1 = (const float*)d_in[4];
    const float* W2 = (const float*)d_in[5];
    const float* b2 = (const float*)d_in[6];
    const float* W3 = (const float*)d_in[7];
    const float* b3 = (const float*)d_in[8];
    float* out = (float*)d_out;
    unsigned short* wsw = (unsigned short*)d_ws;

    const bool bf16nf = (ws_size >= WS_NEED);

    hipLaunchKernelGGL(prep, dim3(1024), dim3(256), 0, stream,
                       W1, b1, W2, W3, nf, wsw, bf16nf ? 1 : 0);

    const int tiles  = NE / 16;                 // 50000
    const int waves  = tiles / TPW;             // 25000
    const int blocks = waves / 4;               // 6250
    if (bf16nf)
        hipLaunchKernelGGL(edge_mlp<true>, dim3(blocks), dim3(256), 0, stream,
                           nf, ei, sp, b2, b3, wsw, out);
    else
        hipLaunchKernelGGL(edge_mlp<false>, dim3(blocks), dim3(256), 0, stream,
                           nf, ei, sp, b2, b3, wsw, out);
}

// Round 4
// 65.850 us; speedup vs baseline: 1.2871x; 1.2871x over previous
//
#include <hip/hip_runtime.h>
#include <hip/hip_bf16.h>

#define NE 800000   // edges
#define NN 50000    // nodes
#define TPW 4       // edge-tiles (of 16 edges) per wave
#define NTILES (NE / 16)       // 50000
#define NODE_TILES (NN / 16)   // 3125

typedef __attribute__((ext_vector_type(8))) short        s16x8;
typedef __attribute__((ext_vector_type(8))) __bf16       bf16x8;
typedef __attribute__((ext_vector_type(4))) float        f32x4;
typedef __attribute__((ext_vector_type(2))) float        f32x2;
typedef __attribute__((ext_vector_type(4))) unsigned int u32x4;
typedef __attribute__((ext_vector_type(2))) unsigned int u32x2;

// ws layout (unsigned short elems):
//   [0)      w1t [64][160]   10240   (k<130: W1^T, else 0)
//   [10240)  w2t [32][64]     2048
//   [12288)  w3t [16][32]      512
//   [16384)  At  [NN][64]  bf16 node table (nf @ W1[0:64])
//   [+NN*64) Bt  [NN][64]  bf16 node table (nf @ W1[64:128])
// fallback (small ws): [16384) nfb [NN][64] bf16 node features
#define TAB_OFF 16384
#define WS_TAB ((size_t)(TAB_OFF + 2ull * NN * 64) * 2)
#define WS_NFB ((size_t)(TAB_OFF + 1ull * NN * 64) * 2)

__device__ __forceinline__ unsigned short f2bf_bits(float f) {
    __bf16 b = (__bf16)f;
    return __builtin_bit_cast(unsigned short, b);
}

__device__ __forceinline__ unsigned int pkbf(float a, float b) {
    return (unsigned int)f2bf_bits(a) | ((unsigned int)f2bf_bits(b) << 16);
}

__device__ __forceinline__ s16x8 cvt8(f32x4 a, f32x4 b) {
    bf16x8 r;
    r[0] = (__bf16)a[0]; r[1] = (__bf16)a[1]; r[2] = (__bf16)a[2]; r[3] = (__bf16)a[3];
    r[4] = (__bf16)b[0]; r[5] = (__bf16)b[1]; r[6] = (__bf16)b[2]; r[7] = (__bf16)b[3];
    return __builtin_bit_cast(s16x8, r);
}

__device__ __forceinline__ void ubf2(unsigned int u, float& lo, float& hi) {
    lo = __builtin_bit_cast(float, u << 16);
    hi = __builtin_bit_cast(float, u & 0xFFFF0000u);
}

__global__ void prep(const float* __restrict__ W1, const float* __restrict__ W2,
                     const float* __restrict__ W3, const float* __restrict__ nf,
                     unsigned short* __restrict__ ws, int do_nf) {
    unsigned short* w1t = ws;
    unsigned short* w2t = ws + 10240;
    unsigned short* w3t = ws + 12288;
    int t = blockIdx.x * blockDim.x + threadIdx.x;
    int stride = gridDim.x * blockDim.x;
    for (int i = t; i < 64 * 160; i += stride) {
        int j = i / 160, k = i % 160;
        w1t[i] = f2bf_bits(k < 130 ? W1[k * 64 + j] : 0.0f);
    }
    for (int i = t; i < 32 * 64; i += stride) {
        int j = i / 64, k = i % 64;
        w2t[i] = f2bf_bits(W2[k * 32 + j]);
    }
    for (int i = t; i < 16 * 32; i += stride) {
        int j = i / 32, k = i % 32;
        w3t[i] = f2bf_bits(W3[k * 16 + j]);
    }
    if (do_nf) {
        unsigned short* nfb = ws + TAB_OFF;
        for (int i = t; i < NN * 8; i += stride) {
            f32x4 a = *reinterpret_cast<const f32x4*>(nf + (long)i * 8);
            f32x4 b = *reinterpret_cast<const f32x4*>(nf + (long)i * 8 + 4);
            *reinterpret_cast<s16x8*>(nfb + (long)i * 8) = cvt8(a, b);
        }
    }
}

// Per-node layer-1 partials: At = nf @ W1[0:64], Bt = nf @ W1[64:128], bf16.
// Swapped MFMA: A-frag = w1t rows (j-major), B-frag = nf^T, D[j][node].
__global__ __launch_bounds__(256) void node_prep(
    const float* __restrict__ nf, const unsigned short* __restrict__ wsw,
    unsigned short* __restrict__ At, unsigned short* __restrict__ Bt) {
    const unsigned short* w1t = wsw;
    const int tid = threadIdx.x, wid = tid >> 6, lane = tid & 63;
    const int lr = lane & 15, lg = lane >> 4;

    s16x8 w1f[4][4];   // s: k-step (0,1 -> src cols; 2,3 -> dst cols), c: j-tile
    #pragma unroll
    for (int s = 0; s < 4; ++s)
        #pragma unroll
        for (int c = 0; c < 4; ++c)
            w1f[s][c] = *reinterpret_cast<const s16x8*>(w1t + (c * 16 + lr) * 160 + s * 32 + lg * 8);

    for (int tile = blockIdx.x * 4 + wid; tile < NODE_TILES; tile += gridDim.x * 4) {
        const int row = tile * 16 + lr;
        const float* p = nf + (long)row * 64;
        s16x8 nfr[2];
        #pragma unroll
        for (int s = 0; s < 2; ++s) {
            f32x4 a = *reinterpret_cast<const f32x4*>(p + s * 32 + lg * 8);
            f32x4 b = *reinterpret_cast<const f32x4*>(p + s * 32 + lg * 8 + 4);
            nfr[s] = cvt8(a, b);
        }
        f32x4 a4[4], b4[4];
        #pragma unroll
        for (int c = 0; c < 4; ++c) { a4[c] = (f32x4){0,0,0,0}; b4[c] = (f32x4){0,0,0,0}; }
        #pragma unroll
        for (int s = 0; s < 2; ++s)
            #pragma unroll
            for (int c = 0; c < 4; ++c) {
                a4[c] = __builtin_amdgcn_mfma_f32_16x16x32_bf16(w1f[s][c],     nfr[s], a4[c], 0, 0, 0);
                b4[c] = __builtin_amdgcn_mfma_f32_16x16x32_bf16(w1f[s + 2][c], nfr[s], b4[c], 0, 0, 0);
            }
        // D: lane holds feat j=c*16+lg*4+r of node=row
        #pragma unroll
        for (int c = 0; c < 4; ++c) {
            u32x2 pa, pb;
            pa[0] = pkbf(a4[c][0], a4[c][1]); pa[1] = pkbf(a4[c][2], a4[c][3]);
            pb[0] = pkbf(b4[c][0], b4[c][1]); pb[1] = pkbf(b4[c][2], b4[c][3]);
            *reinterpret_cast<u32x2*>(At + (long)row * 64 + c * 16 + lg * 4) = pa;
            *reinterpret_cast<u32x2*>(Bt + (long)row * 64 + c * 16 + lg * 4) = pb;
        }
    }
}

__device__ __forceinline__ void gatherT(const unsigned short* At, const unsigned short* Bt,
                                        int si, int di, int lg, s16x8 g[4]) {
    const unsigned short* pa = At + (size_t)si * 64 + lg * 8;
    const unsigned short* pb = Bt + (size_t)di * 64 + lg * 8;
    g[0] = *reinterpret_cast<const s16x8*>(pa);
    g[1] = *reinterpret_cast<const s16x8*>(pa + 32);
    g[2] = *reinterpret_cast<const s16x8*>(pb);
    g[3] = *reinterpret_cast<const s16x8*>(pb + 32);
}

// Main edge kernel, table path. Per lane: h1 feats {jb*32+lg*8..+7} for edge lr,
// computed in f32 directly in the layer-2 B-fragment layout. 5 MFMA/tile total.
__global__ __launch_bounds__(256) void edge_mlp_tab(
    const int* __restrict__ ei, const float* __restrict__ sp,
    const float* __restrict__ W1, const float* __restrict__ b1,
    const float* __restrict__ b2, const float* __restrict__ b3,
    const unsigned short* __restrict__ wsw, float* __restrict__ out) {

    const unsigned short* w2t = wsw + 10240;
    const unsigned short* w3t = wsw + 12288;
    const unsigned short* At  = wsw + TAB_OFF;
    const unsigned short* Bt  = At + (size_t)NN * 64;

    __shared__ unsigned short h2s[4 * 16 * 40];   // 5120 B

    const int tid = threadIdx.x, wid = tid >> 6, lane = tid & 63;
    const int lr = lane & 15, lg = lane >> 4;

    s16x8 w2f[2][2], w3f;
    #pragma unroll
    for (int s = 0; s < 2; ++s)
        #pragma unroll
        for (int c = 0; c < 2; ++c)
            w2f[s][c] = *reinterpret_cast<const s16x8*>(w2t + (c * 16 + lr) * 64 + s * 32 + lg * 8);
    w3f = *reinterpret_cast<const s16x8*>(w3t + lr * 32 + lg * 8);

    f32x4 b2v[2];
    #pragma unroll
    for (int c = 0; c < 2; ++c) b2v[c] = *reinterpret_cast<const f32x4*>(b2 + c * 16 + lg * 4);
    const f32x4 b3v = *reinterpret_cast<const f32x4*>(b3 + lg * 4);

    // spatial/bias consts for this lane's 16 h1 feats (j = jb*32 + lg*8 + 0..7)
    float c0f[2][8], c1f[2][8], cbf[2][8];
    #pragma unroll
    for (int jb = 0; jb < 2; ++jb) {
        const int j0 = jb * 32 + lg * 8;
        *reinterpret_cast<f32x4*>(&c0f[jb][0]) = *reinterpret_cast<const f32x4*>(W1 + 128 * 64 + j0);
        *reinterpret_cast<f32x4*>(&c0f[jb][4]) = *reinterpret_cast<const f32x4*>(W1 + 128 * 64 + j0 + 4);
        *reinterpret_cast<f32x4*>(&c1f[jb][0]) = *reinterpret_cast<const f32x4*>(W1 + 129 * 64 + j0);
        *reinterpret_cast<f32x4*>(&c1f[jb][4]) = *reinterpret_cast<const f32x4*>(W1 + 129 * 64 + j0 + 4);
        *reinterpret_cast<f32x4*>(&cbf[jb][0]) = *reinterpret_cast<const f32x4*>(b1 + j0);
        *reinterpret_cast<f32x4*>(&cbf[jb][4]) = *reinterpret_cast<const f32x4*>(b1 + j0 + 4);
    }

    const int tile0 = (blockIdx.x * 4 + wid) * TPW;
    int si[TPW], di[TPW];
    f32x2 spv[TPW];
    #pragma unroll
    for (int t = 0; t < TPW; ++t) {
        const int e = (tile0 + t) * 16 + lr;
        si[t] = ei[e];
        di[t] = ei[NE + e];
        spv[t] = *reinterpret_cast<const f32x2*>(sp + 2 * (size_t)e);
    }

    unsigned short* h2w = h2s + wid * (16 * 40) + lr * 40;

    s16x8 cur[4], nxt[4];
    gatherT(At, Bt, si[0], di[0], lg, cur);

    #pragma unroll
    for (int tt = 0; tt < TPW; ++tt) {
        if (tt + 1 < TPW)
            gatherT(At, Bt, si[tt + 1], di[tt + 1], lg, nxt);

        const float sp0 = spv[tt][0], sp1 = spv[tt][1];

        // ---- h1 = relu(At[si] + Bt[di] + b1 + sp @ W1c), in B-frag layout ----
        s16x8 bfr[2];
        #pragma unroll
        for (int jb = 0; jb < 2; ++jb) {
            u32x4 au = __builtin_bit_cast(u32x4, cur[jb]);
            u32x4 bu = __builtin_bit_cast(u32x4, cur[2 + jb]);
            u32x4 pk4;
            #pragma unroll
            for (int q = 0; q < 4; ++q) {
                float alo, ahi, blo, bhi;
                ubf2(au[q], alo, ahi);
                ubf2(bu[q], blo, bhi);
                float h0 = fmaf(sp0, c0f[jb][2 * q],
                           fmaf(sp1, c1f[jb][2 * q],     cbf[jb][2 * q]     + (alo + blo)));
                float h1 = fmaf(sp0, c0f[jb][2 * q + 1],
                           fmaf(sp1, c1f[jb][2 * q + 1], cbf[jb][2 * q + 1] + (ahi + bhi)));
                pk4[q] = pkbf(fmaxf(h0, 0.f), fmaxf(h1, 0.f));
            }
            bfr[jb] = __builtin_bit_cast(s16x8, pk4);
        }

        // ---- layer 2 (swapped): 4 MFMA ----
        f32x4 acc2[2];
        #pragma unroll
        for (int c = 0; c < 2; ++c) acc2[c] = (f32x4){0, 0, 0, 0};
        #pragma unroll
        for (int s = 0; s < 2; ++s)
            #pragma unroll
            for (int c = 0; c < 2; ++c)
                acc2[c] = __builtin_amdgcn_mfma_f32_16x16x32_bf16(w2f[s][c], bfr[s], acc2[c], 0, 0, 0);

        #pragma unroll
        for (int c = 0; c < 2; ++c) {
            u32x2 p;
            p[0] = pkbf(fmaxf(acc2[c][0] + b2v[c][0], 0.f), fmaxf(acc2[c][1] + b2v[c][1], 0.f));
            p[1] = pkbf(fmaxf(acc2[c][2] + b2v[c][2], 0.f), fmaxf(acc2[c][3] + b2v[c][3], 0.f));
            *reinterpret_cast<u32x2*>(h2w + c * 16 + lg * 4) = p;
        }

        // ---- layer 3 (swapped): 1 MFMA + coalesced store ----
        s16x8 bf3 = *reinterpret_cast<const s16x8*>(h2w + lg * 8);
        f32x4 acc3 = (f32x4){0, 0, 0, 0};
        acc3 = __builtin_amdgcn_mfma_f32_16x16x32_bf16(w3f, bf3, acc3, 0, 0, 0);

        f32x4 o;
        #pragma unroll
        for (int r = 0; r < 4; ++r) o[r] = acc3[r] + b3v[r];
        __builtin_nontemporal_store(o,
            reinterpret_cast<f32x4*>(out + (long)((tile0 + tt) * 16 + lr) * 16 + lg * 4));

        #pragma unroll
        for (int s = 0; s < 4; ++s) cur[s] = nxt[s];
    }
}

// ---------------- fallback path (R2 kernel, proven 72 us) ----------------
template <bool BF16NF>
__device__ __forceinline__ void gather4(const unsigned short* nfb, const float* nf,
                                        int si, int di, int lg, s16x8 g[4]) {
    if (BF16NF) {
        #pragma unroll
        for (int s = 0; s < 4; ++s) {
            const int row = (s < 2) ? si : di;
            g[s] = *reinterpret_cast<const s16x8*>(nfb + (long)row * 64 + (s & 1) * 32 + lg * 8);
        }
    } else {
        #pragma unroll
        for (int s = 0; s < 4; ++s) {
            const float* p = nf + (long)((s < 2) ? si : di) * 64 + (s & 1) * 32 + lg * 8;
            f32x4 a = *reinterpret_cast<const f32x4*>(p);
            f32x4 b = *reinterpret_cast<const f32x4*>(p + 4);
            g[s] = cvt8(a, b);
        }
    }
}

template <bool BF16NF>
__global__ __launch_bounds__(256) void edge_mlp_fb(
    const float* __restrict__ nf, const int* __restrict__ ei,
    const float* __restrict__ sp, const float* __restrict__ b1,
    const float* __restrict__ b2, const float* __restrict__ b3,
    const unsigned short* __restrict__ wsw, float* __restrict__ out) {

    const unsigned short* w1t = wsw;
    const unsigned short* w2t = wsw + 10240;
    const unsigned short* w3t = wsw + 12288;
    const unsigned short* nfb = wsw + TAB_OFF;

    __shared__ float h1s[4][16][68];
    __shared__ float h2s[4][16][36];

    const int tid = threadIdx.x, wid = tid >> 6, lane = tid & 63;
    const int lr = lane & 15, lg = lane >> 4;

    s16x8 w1f[5][4], w2f[2][2], w3f;
    #pragma unroll
    for (int s = 0; s < 5; ++s)
        #pragma unroll
        for (int c = 0; c < 4; ++c)
            w1f[s][c] = *reinterpret_cast<const s16x8*>(w1t + (c * 16 + lr) * 160 + s * 32 + lg * 8);
    #pragma unroll
    for (int s = 0; s < 2; ++s)
        #pragma unroll
        for (int c = 0; c < 2; ++c)
            w2f[s][c] = *reinterpret_cast<const s16x8*>(w2t + (c * 16 + lr) * 64 + s * 32 + lg * 8);
    w3f = *reinterpret_cast<const s16x8*>(w3t + lr * 32 + lg * 8);

    float bias1[4], bias2[2], bias3;
    #pragma unroll
    for (int c = 0; c < 4; ++c) bias1[c] = b1[c * 16 + lr];
    #pragma unroll
    for (int c = 0; c < 2; ++c) bias2[c] = b2[c * 16 + lr];
    bias3 = b3[lr];

    const int tile0 = (blockIdx.x * 4 + wid) * TPW;
    int si[TPW], di[TPW];
    f32x2 spv[TPW];
    #pragma unroll
    for (int t = 0; t < TPW; ++t) {
        const int e = (tile0 + t) * 16 + lr;
        si[t] = ei[e];
        di[t] = ei[NE + e];
        spv[t] = *reinterpret_cast<const f32x2*>(sp + 2 * (size_t)e);
    }

    s16x8 cur[4], nxt[4];
    gather4<BF16NF>(nfb, nf, si[0], di[0], lg, cur);

    #pragma unroll
    for (int tt = 0; tt < TPW; ++tt) {
        if (tt + 1 < TPW)
            gather4<BF16NF>(nfb, nf, si[tt + 1], di[tt + 1], lg, nxt);

        const int ebase = (tile0 + tt) * 16;

        f32x4 acc1[4];
        #pragma unroll
        for (int c = 0; c < 4; ++c) acc1[c] = (f32x4){0, 0, 0, 0};
        #pragma unroll
        for (int s = 0; s < 4; ++s)
            #pragma unroll
            for (int c = 0; c < 4; ++c)
                acc1[c] = __builtin_amdgcn_mfma_f32_16x16x32_bf16(cur[s], w1f[s][c], acc1[c], 0, 0, 0);
        {
            bf16x8 z;
            #pragma unroll
            for (int j = 0; j < 8; ++j) z[j] = (__bf16)0.0f;
            if (lg == 0) { z[0] = (__bf16)spv[tt][0]; z[1] = (__bf16)spv[tt][1]; }
            s16x8 af = __builtin_bit_cast(s16x8, z);
            #pragma unroll
            for (int c = 0; c < 4; ++c)
                acc1[c] = __builtin_amdgcn_mfma_f32_16x16x32_bf16(af, w1f[4][c], acc1[c], 0, 0, 0);
        }
        #pragma unroll
        for (int c = 0; c < 4; ++c)
            #pragma unroll
            for (int r = 0; r < 4; ++r)
                h1s[wid][lg * 4 + r][c * 16 + lr] = fmaxf(acc1[c][r] + bias1[c], 0.0f);

        f32x4 acc2[2];
        #pragma unroll
        for (int c = 0; c < 2; ++c) acc2[c] = (f32x4){0, 0, 0, 0};
        #pragma unroll
        for (int s = 0; s < 2; ++s) {
            f32x4 a = *reinterpret_cast<const f32x4*>(&h1s[wid][lr][s * 32 + lg * 8]);
            f32x4 b = *reinterpret_cast<const f32x4*>(&h1s[wid][lr][s * 32 + lg * 8 + 4]);
            s16x8 af = cvt8(a, b);
            #pragma unroll
            for (int c = 0; c < 2; ++c)
                acc2[c] = __builtin_amdgcn_mfma_f32_16x16x32_bf16(af, w2f[s][c], acc2[c], 0, 0, 0);
        }
        #pragma unroll
        for (int c = 0; c < 2; ++c)
            #pragma unroll
            for (int r = 0; r < 4; ++r)
                h2s[wid][lg * 4 + r][c * 16 + lr] = fmaxf(acc2[c][r] + bias2[c], 0.0f);

        f32x4 a3 = *reinterpret_cast<const f32x4*>(&h2s[wid][lr][lg * 8]);
        f32x4 b3x = *reinterpret_cast<const f32x4*>(&h2s[wid][lr][lg * 8 + 4]);
        s16x8 af3 = cvt8(a3, b3x);
        f32x4 acc3 = (f32x4){0, 0, 0, 0};
        acc3 = __builtin_amdgcn_mfma_f32_16x16x32_bf16(af3, w3f, acc3, 0, 0, 0);
        #pragma unroll
        for (int r = 0; r < 4; ++r)
            out[(long)(ebase + lg * 4 + r) * 16 + lr] = acc3[r] + bias3;

        #pragma unroll
        for (int s = 0; s < 4; ++s) cur[s] = nxt[s];
    }
}

extern "C" void kernel_launch(void* const* d_in, const int* in_sizes, int n_in,
                              void* d_out, int out_size, void* d_ws, size_t ws_size,
                              hipStream_t stream) {
    const float* nf = (const float*)d_in[0];
    const int*   ei = (const int*)d_in[1];
    const float* sp = (const float*)d_in[2];
    const float* W1 = (const float*)d_in[3];
    const float* b1 = (const float*)d_in[4];
    const float* W2 = (const float*)d_in[5];
    const float* b2 = (const float*)d_in[6];
    const float* W3 = (const float*)d_in[7];
    const float* b3 = (const float*)d_in[8];
    float* out = (float*)d_out;
    unsigned short* wsw = (unsigned short*)d_ws;

    const bool tab  = (ws_size >= WS_TAB);
    const bool bnfb = (!tab && ws_size >= WS_NFB);

    hipLaunchKernelGGL(prep, dim3(64), dim3(256), 0, stream,
                       W1, W2, W3, nf, wsw, bnfb ? 1 : 0);

    const int blocks = NTILES / TPW / 4;   // 3125
    if (tab) {
        hipLaunchKernelGGL(node_prep, dim3(196), dim3(256), 0, stream,
                           nf, wsw, wsw + TAB_OFF, wsw + TAB_OFF + (size_t)NN * 64);
        hipLaunchKernelGGL(edge_mlp_tab, dim3(blocks), dim3(256), 0, stream,
                           ei, sp, W1, b1, b2, b3, wsw, out);
    } else if (bnfb) {
        hipLaunchKernelGGL(edge_mlp_fb<true>, dim3(blocks), dim3(256), 0, stream,
                           nf, ei, sp, b1, b2, b3, wsw, out);
    } else {
        hipLaunchKernelGGL(edge_mlp_fb<false>, dim3(blocks), dim3(256), 0, stream,
                           nf, ei, sp, b1, b2, b3, wsw, out);
    }
}